// Round 1
// baseline (43.001 us; speedup 1.0000x reference)
//
#include <hip/hip_runtime.h>
#include <hip/hip_bf16.h>

// VQ-VAE quantize: x[32,64,64,64] NCHW fp32, codebook[512,64] fp32.
// d_out[0] = 1.25 * SSD / 8388608 ; d_out[1..] = codebook[argmin] in NCHW.
// Plan: per block 256 rows; bf16 MFMA 16x16x32 for dot(x, c); argmin of
// (||c||^2 - 2 dot) via argmax of (dot - ||c||^2/2) with bias in MFMA C-in.

typedef __attribute__((ext_vector_type(8))) __bf16 bf16x8;
typedef __attribute__((ext_vector_type(4))) float f32x4;

#define CB_OFF   0
#define XA_OFF   32768
#define HN2_OFF  65536
#define IDX_OFF  67584
#define RED_OFF  68608
#define SMEM_SZ  68672

__device__ __forceinline__ unsigned f2b1(float f) {
  unsigned u = __float_as_uint(f);
  return (u + 0x7FFFu + ((u >> 16) & 1)) >> 16;   // RNE float->bf16 bits
}
__device__ __forceinline__ unsigned pack2(float lo, float hi) {
  return f2b1(lo) | (f2b1(hi) << 16);
}
__device__ __forceinline__ int swz(int row) {    // XOR swizzle, 16B granules
  return ((row & 7) ^ ((row >> 4) & 7)) << 4;
}

__global__ void __launch_bounds__(256, 2)
vq_main(const float* __restrict__ x, const float* __restrict__ cb,
        float* __restrict__ out, float* __restrict__ ws) {
  __shared__ __align__(16) char smem[SMEM_SZ];
  char*  cbz  = smem + CB_OFF;          // bf16 [256][64] swizzled (one half)
  char*  xaz  = smem + XA_OFF;          // bf16 [256][64] swizzled
  float* hn2z = (float*)(smem + HN2_OFF); // -0.5*||c||^2, all 512
  int*   idxz = (int*)(smem + IDX_OFF);
  float* redz = (float*)(smem + RED_OFF);
  float* qldz = (float*)smem;           // phase-B overlay: fp32 [256][65]

  const int t    = threadIdx.x;
  const int bid  = blockIdx.x;
  const int bimg = bid >> 4;            // batch index
  const int hw0  = (bid & 15) << 8;     // h*64+w tile start
  const float*  xb  = x + (bimg << 18) + hw0;
  const float4* xb4 = (const float4*)xb;
  const float4* cb4 = (const float4*)cb;

  // ---- stage X tile: read [d][rows] coalesced, write bf16 [row][d] swizzled
  {
    const int r0 = (t & 15) << 4;
    const int dp = t >> 4;                       // 0..15
    #pragma unroll
    for (int dd = 0; dd < 2; ++dd) {
      const int p  = dp + (dd << 4);             // d-pair index 0..31
      const int d0 = p << 1;
      #pragma unroll
      for (int j = 0; j < 4; ++j) {
        float4 A0 = xb4[(d0 << 10) + (r0 >> 2) + j];
        float4 A1 = xb4[((d0 + 1) << 10) + (r0 >> 2) + j];
        const float* a0 = (const float*)&A0;
        const float* a1 = (const float*)&A1;
        #pragma unroll
        for (int u = 0; u < 4; ++u) {
          int r = r0 + (j << 2) + u;
          *(unsigned*)(xaz + r * 128 + ((p << 2) ^ swz(r))) = pack2(a0[u], a1[u]);
        }
      }
    }
  }
  // ---- hn2 for all 512 codes (fp32 from global, L2-hot) ----
  {
    #pragma unroll
    for (int q = 0; q < 2; ++q) {
      int n = t + (q << 8);
      float s = 0.f;
      #pragma unroll
      for (int j = 0; j < 16; ++j) {
        float4 v = cb4[(n << 4) + j];
        s += v.x * v.x + v.y * v.y + v.z * v.z + v.w * v.w;
      }
      hn2z[n] = -0.5f * s;
    }
  }
  // ---- stage codebook half 0 (codes 0..255) as bf16 swizzled ----
  {
    #pragma unroll
    for (int i = 0; i < 8; ++i) {
      int cid = (i << 8) + t;
      int rloc = cid >> 3;
      int kb = (cid & 7) << 4;
      float4 f0 = cb4[(rloc << 4) + ((cid & 7) << 1)];
      float4 f1 = cb4[(rloc << 4) + ((cid & 7) << 1) + 1];
      uint4 u;
      u.x = pack2(f0.x, f0.y); u.y = pack2(f0.z, f0.w);
      u.z = pack2(f1.x, f1.y); u.w = pack2(f1.z, f1.w);
      *(uint4*)(cbz + rloc * 128 + (kb ^ swz(rloc))) = u;
    }
  }
  __syncthreads();

  const int lane = t & 63;
  const int wid  = t >> 6;
  const int lrow = lane & 15;
  const int lk2  = (lane >> 4) << 4;   // byte offset of this lane's k-group
  const int swl  = (lrow & 7) << 4;

  // A fragments: 4 subtiles x 2 k-steps, persist in regs
  bf16x8 af[4][2];
  #pragma unroll
  for (int s = 0; s < 4; ++s) {
    int row = (wid << 6) + (s << 4) + lrow;
    int sw = swz(row);
    af[s][0] = *(const bf16x8*)(xaz + row * 128 + (lk2 ^ sw));
    af[s][1] = *(const bf16x8*)(xaz + row * 128 + ((lk2 ^ 64) ^ sw));
  }

  float bestv[4][4];
  int   besti[4][4];
  #pragma unroll
  for (int s = 0; s < 4; ++s)
    #pragma unroll
    for (int r = 0; r < 4; ++r) { bestv[s][r] = -3.0e38f; besti[s][r] = 0; }

  const int cbo0 = lrow * 128 + (lk2 ^ swl);
  const int cbo1 = lrow * 128 + ((lk2 ^ 64) ^ swl);

  for (int h = 0; h < 2; ++h) {
    if (h) {
      __syncthreads();                 // everyone done reading half 0
      #pragma unroll
      for (int i = 0; i < 8; ++i) {    // stage codebook half 1
        int cid = (i << 8) + t;
        int rloc = cid >> 3;
        int kb = (cid & 7) << 4;
        float4 f0 = cb4[((rloc + 256) << 4) + ((cid & 7) << 1)];
        float4 f1 = cb4[((rloc + 256) << 4) + ((cid & 7) << 1) + 1];
        uint4 u;
        u.x = pack2(f0.x, f0.y); u.y = pack2(f0.z, f0.w);
        u.z = pack2(f1.x, f1.y); u.w = pack2(f1.z, f1.w);
        *(uint4*)(cbz + rloc * 128 + (kb ^ swz(rloc))) = u;
      }
      __syncthreads();
    }
    #pragma unroll 4
    for (int c = 0; c < 16; ++c) {
      const int c7 = (c & 7) << 4;
      const char* bp = cbz + c * 2048;
      bf16x8 b0 = *(const bf16x8*)(bp + (cbo0 ^ c7));
      bf16x8 b1 = *(const bf16x8*)(bp + (cbo1 ^ c7));
      const int nc = (h << 8) + (c << 4) + lrow;
      const float hv = hn2z[nc];
      #pragma unroll
      for (int s = 0; s < 4; ++s) {
        f32x4 acc = {hv, hv, hv, hv};
        acc = __builtin_amdgcn_mfma_f32_16x16x32_bf16(af[s][0], b0, acc, 0, 0, 0);
        acc = __builtin_amdgcn_mfma_f32_16x16x32_bf16(af[s][1], b1, acc, 0, 0, 0);
        #pragma unroll
        for (int r = 0; r < 4; ++r) {
          if (acc[r] > bestv[s][r]) { bestv[s][r] = acc[r]; besti[s][r] = nc; }
        }
      }
    }
  }

  // cross-lane argmax over the 16 column slots (first-index tie-break)
  #pragma unroll
  for (int s = 0; s < 4; ++s) {
    #pragma unroll
    for (int r = 0; r < 4; ++r) {
      float v = bestv[s][r];
      int  id = besti[s][r];
      #pragma unroll
      for (int m = 1; m <= 8; m <<= 1) {
        float pv = __shfl_xor(v, m, 64);
        int   pi = __shfl_xor(id, m, 64);
        if (pv > v || (pv == v && pi < id)) { v = pv; id = pi; }
      }
      if (lrow == 0)
        idxz[(wid << 6) + (s << 4) + ((lane >> 4) << 2) + r] = id;
    }
  }
  __syncthreads();

  // ---- phase B: gather codebook rows, write NCHW coalesced, loss ----
  const int myidx = idxz[t];
  float* outq = out + 1 + (bimg << 18) + hw0;
  {
    const float4* cbr = cb4 + (myidx << 4);
    float* qrow = qldz + t * 65;
    #pragma unroll
    for (int j = 0; j < 16; ++j) {
      float4 v = cbr[j];
      qrow[(j << 2) + 0] = v.x; qrow[(j << 2) + 1] = v.y;
      qrow[(j << 2) + 2] = v.z; qrow[(j << 2) + 3] = v.w;
    }
  }
  float lsum = 0.f;
  for (int d = 0; d < 64; ++d) {
    float xv = xb[(d << 12) + t];          // coalesced, L2-hot
    float qv = qldz[t * 65 + d];           // 2-way bank at worst
    outq[(d << 12) + t] = qv;              // coalesced dword store
    float df = qv - xv;
    lsum = fmaf(df, df, lsum);
  }
  #pragma unroll
  for (int m = 32; m; m >>= 1) lsum += __shfl_xor(lsum, m, 64);
  if (lane == 0) redz[wid] = lsum;
  __syncthreads();
  if (t == 0) ws[bid] = redz[0] + redz[1] + redz[2] + redz[3];
}

__global__ void vq_finalize(const float* __restrict__ ws, float* __restrict__ out) {
  int t = threadIdx.x;
  __shared__ float red[4];
  float v = ws[t] + ws[t + 256];
  #pragma unroll
  for (int m = 32; m; m >>= 1) v += __shfl_xor(v, m, 64);
  if ((t & 63) == 0) red[t >> 6] = v;
  __syncthreads();
  if (t == 0) out[0] = (red[0] + red[1] + red[2] + red[3]) * (1.25f / 8388608.0f);
}

extern "C" void kernel_launch(void* const* d_in, const int* in_sizes, int n_in,
                              void* d_out, int out_size, void* d_ws, size_t ws_size,
                              hipStream_t stream) {
  const float* x  = (const float*)d_in[0];   // 32*64*64*64 fp32 NCHW
  const float* cb = (const float*)d_in[1];   // 512*64 fp32
  float* out = (float*)d_out;                // [0]=loss, [1..]=quantized NCHW
  float* ws  = (float*)d_ws;                 // 512 partial loss sums
  vq_main<<<512, 256, 0, stream>>>(x, cb, out, ws);
  vq_finalize<<<1, 256, 0, stream>>>(ws, out);
}